// Round 1
// baseline (110.467 us; speedup 1.0000x reference)
//
#include <hip/hip_runtime.h>

typedef __attribute__((ext_vector_type(8))) short s16x8;
typedef __attribute__((ext_vector_type(4))) float f32x4;
typedef __attribute__((ext_vector_type(2))) unsigned int u32x2;

#define MFMA16(a, b, c) __builtin_amdgcn_mfma_f32_16x16x32_bf16((a), (b), (c), 0, 0, 0)

static __device__ __forceinline__ unsigned short f2bf(float f) {
  unsigned int u = __float_as_uint(f);
  u += 0x7fffu + ((u >> 16) & 1u);   // round-to-nearest-even
  return (unsigned short)(u >> 16);
}
static __device__ __forceinline__ int div7(int x) { return (x * 9363) >> 16; }  // exact for 0..62
static __device__ __forceinline__ int swz256(int row, int byteoff) {
  return row * 256 + (byteoff ^ ((row & 7) << 4));
}
static __device__ __forceinline__ int swz128(int row, int byteoff) {
  return row * 128 + (byteoff ^ ((row & 7) << 4));
}

// ---------------- pre-kernel: weights fp32->bf16 into ws; expand rpb ----------------
__global__ void swin_prep(const float* __restrict__ wq, const float* __restrict__ wk,
                          const float* __restrict__ wv, const float* __restrict__ wp,
                          const float* __restrict__ rpb_table,
                          unsigned short* __restrict__ wsW, float* __restrict__ rpbx) {
  int idx = blockIdx.x * 256 + threadIdx.x;
  if (idx < 65536) {
    int t = idx >> 14, loc = idx & 16383;
    const float* s = (t == 0) ? wq : (t == 1) ? wk : (t == 2) ? wv : wp;
    wsW[idx] = f2bf(s[loc]);
  } else {
    int k = idx - 65536;
    if (k < 4 * 49 * 49) {
      int h = k / 2401, rem = k - h * 2401;
      int i = rem / 49, j = rem - i * 49;
      int yi = i / 7, xi = i % 7, yj = j / 7, xj = j % 7;
      int ridx = (yi - yj + 6) * 13 + (xi - xj + 6);
      rpbx[k] = rpb_table[ridx * 4 + h];
    }
  }
}

// ---------------- main kernel: one workgroup per (batch, window) ----------------
__global__ __launch_bounds__(256, 2) void swin_main(
    const float* __restrict__ xq, const float* __restrict__ xk, const float* __restrict__ xv,
    const float* __restrict__ bq, const float* __restrict__ bk, const float* __restrict__ bv,
    const float* __restrict__ bp, const unsigned short* __restrict__ wsW,
    const float* __restrict__ rpbx, float* __restrict__ out) {
  // LDS regions (bytes): R0 [0,16K): X then O ; R1 [16K,32K): Q then P(h=0,1)
  // R2 [32K,48K): K then P(h=2,3) ; R3 [48K,64K): V^T [128ch][64tok]
  __shared__ __align__(16) char sm[65536];

  const int tid = threadIdx.x;
  const int lane = tid & 63;
  const int wv_ = tid >> 6;       // wave id 0..3
  const int l15 = lane & 15;
  const int lg = lane >> 4;       // 0..3
  const int kgrp = lg * 8;        // k sub-offset inside a 32-wide k-step
  const int rsub = lg * 4;        // C/D row sub-base

  const int bid = blockIdx.x;
  const int b = bid >> 6;
  const int widx = bid & 63;
  const int wi = widx >> 3, wj = widx & 7;
  const long obase = (long)b * 56 * 56 * 128;

  // ---- Phase A loader: rolled gather fp32 -> bf16, rows >=49 zeroed ----
  auto load_x = [&](const float* src) {
#pragma unroll
    for (int it = 0; it < 8; ++it) {
      int chunk = it * 256 + tid;   // 2048 chunks of 4 elems
      int row = chunk >> 5;
      int k4 = (chunk & 31) << 2;
      unsigned int lo = 0, hi = 0;
      if (row < 49) {
        int ty = div7(row), tx = row - ty * 7;
        int ih = wi * 7 + ty + 3; if (ih >= 56) ih -= 56;
        int iw = wj * 7 + tx + 3; if (iw >= 56) iw -= 56;
        const float* p = src + ((ih * 56 + iw) * 128 + k4);
        float v0 = p[0], v1 = p[1], v2 = p[2], v3 = p[3];
        lo = (unsigned int)f2bf(v0) | ((unsigned int)f2bf(v1) << 16);
        hi = (unsigned int)f2bf(v2) | ((unsigned int)f2bf(v3) << 16);
      }
      u32x2 pk = {lo, hi};
      *(u32x2*)(sm + swz256(row, k4 * 2)) = pk;
    }
  };

  // ---- Phase B: y = X @ W^T + bias (waves split over N) ----
  // mode 0: row-major bf16 to sm+dstbase ; mode 1: transposed (V^T) to R3
  auto linear = [&](int woff, const float* bias, float scale, int mode, int dstbase) {
#pragma unroll
    for (int nt2 = 0; nt2 < 2; ++nt2) {
      int n = wv_ * 32 + nt2 * 16 + l15;
      s16x8 bfr[4];
#pragma unroll
      for (int kt = 0; kt < 4; ++kt)
        bfr[kt] = *(const s16x8*)(wsW + woff + n * 128 + kt * 32 + kgrp);
      float bval = bias[n] * scale;
#pragma unroll
      for (int mt = 0; mt < 4; ++mt) {
        int arow = mt * 16 + l15;
        f32x4 acc = {0.f, 0.f, 0.f, 0.f};
#pragma unroll
        for (int kt = 0; kt < 4; ++kt) {
          s16x8 afr = *(const s16x8*)(sm + swz256(arow, (kt * 32 + kgrp) * 2));
          acc = MFMA16(afr, bfr[kt], acc);
        }
#pragma unroll
        for (int r = 0; r < 4; ++r) {
          float val = acc[r] * scale + bval;
          unsigned short h16 = f2bf(val);
          int row = mt * 16 + rsub + r;   // token index
          if (mode == 0)
            *(unsigned short*)(sm + dstbase + swz256(row, 2 * n)) = h16;
          else
            *(unsigned short*)(sm + 49152 + swz128(n, 2 * row)) = h16;
        }
      }
    }
  };

  const float QSCALE = 0.17677669529663687f;  // 32^-0.5

  load_x(xq + obase); __syncthreads();
  linear(0, bq, QSCALE, 0, 16384); __syncthreads();
  load_x(xk + obase); __syncthreads();
  linear(16384, bk, 1.f, 0, 32768); __syncthreads();
  load_x(xv + obase); __syncthreads();
  linear(32768, bv, 1.f, 1, 0); __syncthreads();

  // ---- Phase C: per-head attention (wave h = head h) ----
  {
    const int h = wv_;
    const int coff = h * 32;
    // QK^T : S[mt][jt] tiles
    s16x8 kfr[4];
#pragma unroll
    for (int jt = 0; jt < 4; ++jt)
      kfr[jt] = *(const s16x8*)(sm + 32768 + swz256(jt * 16 + l15, (coff + kgrp) * 2));
    f32x4 S[4][4];
#pragma unroll
    for (int mt = 0; mt < 4; ++mt) {
      s16x8 qfr = *(const s16x8*)(sm + 16384 + swz256(mt * 16 + l15, (coff + kgrp) * 2));
#pragma unroll
      for (int jt = 0; jt < 4; ++jt) {
        f32x4 z = {0.f, 0.f, 0.f, 0.f};
        S[mt][jt] = MFMA16(qfr, kfr[jt], z);
      }
    }
    // rpb + shift mask + pad-key masking
    const float* rpbh = rpbx + h * 2401;
    int jj[4], rgj[4]; bool jvld[4];
#pragma unroll
    for (int jt = 0; jt < 4; ++jt) {
      int j = jt * 16 + l15;
      jj[jt] = j; jvld[jt] = (j < 49);
      int jc = jvld[jt] ? j : 0;
      int yj = div7(jc), xj = jc - yj * 7;
      rgj[jt] = ((wi == 7) ? (yj < 4 ? 3 : 6) : 0) + ((wj == 7) ? (xj < 4 ? 1 : 2) : 0);
    }
#pragma unroll
    for (int mt = 0; mt < 4; ++mt) {
#pragma unroll
      for (int r = 0; r < 4; ++r) {
        int i = mt * 16 + rsub + r;
        if (i < 49) {
          int yi = div7(i), xi = i - yi * 7;
          int rgi = ((wi == 7) ? (yi < 4 ? 3 : 6) : 0) + ((wj == 7) ? (xi < 4 ? 1 : 2) : 0);
#pragma unroll
          for (int jt = 0; jt < 4; ++jt) {
            if (jvld[jt]) {
              float sv = S[mt][jt][r] + rpbh[i * 49 + jj[jt]];
              if (rgi != rgj[jt]) sv -= 100.f;
              S[mt][jt][r] = sv;
            } else {
              S[mt][jt][r] = -1e30f;
            }
          }
        } else {
#pragma unroll
          for (int jt = 0; jt < 4; ++jt)
            if (!jvld[jt]) S[mt][jt][r] = -1e30f;
        }
      }
    }
    // row softmax: reduce over 4 jt regs + 16-lane group shuffles
#pragma unroll
    for (int mt = 0; mt < 4; ++mt) {
#pragma unroll
      for (int r = 0; r < 4; ++r) {
        float m = fmaxf(fmaxf(S[mt][0][r], S[mt][1][r]), fmaxf(S[mt][2][r], S[mt][3][r]));
        for (int d = 1; d < 16; d <<= 1) m = fmaxf(m, __shfl_xor(m, d));
        float e0 = __expf(S[mt][0][r] - m);
        float e1 = __expf(S[mt][1][r] - m);
        float e2 = __expf(S[mt][2][r] - m);
        float e3 = __expf(S[mt][3][r] - m);
        float s = e0 + e1 + e2 + e3;
        for (int d = 1; d < 16; d <<= 1) s += __shfl_xor(s, d);
        float inv = 1.0f / s;
        S[mt][0][r] = e0 * inv; S[mt][1][r] = e1 * inv;
        S[mt][2][r] = e2 * inv; S[mt][3][r] = e3 * inv;
      }
    }
    __syncthreads();   // all waves done reading Q/K before P overwrites them
    const int pbase = 16384 + h * 8192;  // P[64][64] bf16, swizzled, per wave
#pragma unroll
    for (int mt = 0; mt < 4; ++mt)
#pragma unroll
      for (int r = 0; r < 4; ++r) {
        int i = mt * 16 + rsub + r;
#pragma unroll
        for (int jt = 0; jt < 4; ++jt)
          *(unsigned short*)(sm + pbase + swz128(i, 2 * (jt * 16 + l15))) = f2bf(S[mt][jt][r]);
      }
    __syncthreads();
    // PV : O = P @ V  (V^T in R3 so B-frags are contiguous)
    s16x8 vfr[2][2];
#pragma unroll
    for (int ks = 0; ks < 2; ++ks)
#pragma unroll
      for (int nt = 0; nt < 2; ++nt) {
        int c = coff + nt * 16 + l15;
        vfr[ks][nt] = *(const s16x8*)(sm + 49152 + swz128(c, (ks * 32 + kgrp) * 2));
      }
    f32x4 Oacc[4][2];
#pragma unroll
    for (int mt = 0; mt < 4; ++mt)
#pragma unroll
      for (int nt = 0; nt < 2; ++nt) Oacc[mt][nt] = (f32x4){0.f, 0.f, 0.f, 0.f};
#pragma unroll
    for (int mt = 0; mt < 4; ++mt) {
#pragma unroll
      for (int ks = 0; ks < 2; ++ks) {
        s16x8 pfr = *(const s16x8*)(sm + pbase + swz128(mt * 16 + l15, (ks * 32 + kgrp) * 2));
        Oacc[mt][0] = MFMA16(pfr, vfr[ks][0], Oacc[mt][0]);
        Oacc[mt][1] = MFMA16(pfr, vfr[ks][1], Oacc[mt][1]);
      }
    }
    // O (bf16, row-major) into R0 (X buffer is dead)
#pragma unroll
    for (int mt = 0; mt < 4; ++mt)
#pragma unroll
      for (int nt = 0; nt < 2; ++nt)
#pragma unroll
        for (int r = 0; r < 4; ++r) {
          int row = mt * 16 + rsub + r;
          int c = coff + nt * 16 + l15;
          *(unsigned short*)(sm + swz256(row, 2 * c)) = f2bf(Oacc[mt][nt][r]);
        }
    __syncthreads();
  }

  // ---- Phase D: proj + rolled scatter to global ----
  {
    const int woff = 49152;
#pragma unroll
    for (int nt2 = 0; nt2 < 2; ++nt2) {
      int n = wv_ * 32 + nt2 * 16 + l15;
      s16x8 bfr[4];
#pragma unroll
      for (int kt = 0; kt < 4; ++kt)
        bfr[kt] = *(const s16x8*)(wsW + woff + n * 128 + kt * 32 + kgrp);
      float bval = bp[n];
#pragma unroll
      for (int mt = 0; mt < 4; ++mt) {
        f32x4 acc = {0.f, 0.f, 0.f, 0.f};
#pragma unroll
        for (int kt = 0; kt < 4; ++kt) {
          s16x8 afr = *(const s16x8*)(sm + swz256(mt * 16 + l15, (kt * 32 + kgrp) * 2));
          acc = MFMA16(afr, bfr[kt], acc);
        }
#pragma unroll
        for (int r = 0; r < 4; ++r) {
          int tok = mt * 16 + rsub + r;
          if (tok < 49) {
            int ty = div7(tok), tx = tok - ty * 7;
            int oh = wi * 7 + ty + 3; if (oh >= 56) oh -= 56;
            int ow = wj * 7 + tx + 3; if (ow >= 56) ow -= 56;
            out[obase + (oh * 56 + ow) * 128 + n] = acc[r] + bval;
          }
        }
      }
    }
  }
}

extern "C" void kernel_launch(void* const* d_in, const int* in_sizes, int n_in,
                              void* d_out, int out_size, void* d_ws, size_t ws_size,
                              hipStream_t stream) {
  const float* xq = (const float*)d_in[0];
  const float* xk = (const float*)d_in[1];
  const float* xv = (const float*)d_in[2];
  const float* wq = (const float*)d_in[3];
  const float* bq = (const float*)d_in[4];
  const float* wk = (const float*)d_in[5];
  const float* bk = (const float*)d_in[6];
  const float* wv = (const float*)d_in[7];
  const float* bv = (const float*)d_in[8];
  const float* wp = (const float*)d_in[9];
  const float* bp = (const float*)d_in[10];
  const float* rpb = (const float*)d_in[11];

  unsigned short* wsW = (unsigned short*)d_ws;                 // 4 x 16384 bf16 = 128 KB
  float* rpbx = (float*)((char*)d_ws + 131072);                // 4*49*49 fp32 = 38.4 KB

  swin_prep<<<294, 256, 0, stream>>>(wq, wk, wv, wp, rpb, wsW, rpbx);

  float* out = (float*)d_out;
  swin_main<<<2048, 256, 0, stream>>>(xq, xk, xv, bq, bk, bv, bp, wsW, rpbx, out);
}

// Round 2
// 90.648 us; speedup vs baseline: 1.2186x; 1.2186x over previous
//
#include <hip/hip_runtime.h>

typedef __attribute__((ext_vector_type(8))) short s16x8;
typedef __attribute__((ext_vector_type(4))) float f32x4;
typedef __attribute__((ext_vector_type(4))) unsigned int u32x4;

#define MFMA16(a, b, c) __builtin_amdgcn_mfma_f32_16x16x32_bf16((a), (b), (c), 0, 0, 0)

static __device__ __forceinline__ unsigned short f2bf(float f) {
  unsigned int u = __float_as_uint(f);
  u += 0x7fffu + ((u >> 16) & 1u);   // round-to-nearest-even
  return (unsigned short)(u >> 16);
}
static __device__ __forceinline__ int div7(int x) { return (x * 9363) >> 16; }  // exact for 0..62
static __device__ __forceinline__ int swz256(int row, int byteoff) {
  return row * 256 + (byteoff ^ ((row & 7) << 4));
}
static __device__ __forceinline__ int swz128(int row, int byteoff) {
  return row * 128 + (byteoff ^ ((row & 7) << 4));
}

// ---------------- pre-kernel: weights fp32->bf16 into ws; expand rpb ----------------
__global__ void swin_prep(const float* __restrict__ wq, const float* __restrict__ wk,
                          const float* __restrict__ wv, const float* __restrict__ wp,
                          const float* __restrict__ rpb_table,
                          unsigned short* __restrict__ wsW, float* __restrict__ rpbx) {
  int idx = blockIdx.x * 256 + threadIdx.x;
  if (idx < 65536) {
    int t = idx >> 14, loc = idx & 16383;
    const float* s = (t == 0) ? wq : (t == 1) ? wk : (t == 2) ? wv : wp;
    wsW[idx] = f2bf(s[loc]);
  } else {
    int k = idx - 65536;
    if (k < 4 * 49 * 49) {
      int h = k / 2401, rem = k - h * 2401;
      int i = rem / 49, j = rem - i * 49;
      int yi = i / 7, xi = i % 7, yj = j / 7, xj = j % 7;
      int ridx = (yi - yj + 6) * 13 + (xi - xj + 6);
      rpbx[k] = rpb_table[ridx * 4 + h];
    }
  }
}

// ---------------- main kernel: one 512-thread workgroup per (batch, window) ----------------
__global__ __launch_bounds__(512, 4) void swin_main(
    const float* __restrict__ xq, const float* __restrict__ xk, const float* __restrict__ xv,
    const float* __restrict__ bq, const float* __restrict__ bk, const float* __restrict__ bv,
    const float* __restrict__ bp, const unsigned short* __restrict__ wsW,
    const float* __restrict__ rpbx, float* __restrict__ out) {
  // LDS regions (bytes): R0 [0,16K): X then O ; R1 [16K,32K): Q then P(h=0,1)
  // R2 [32K,48K): K then P(h=2,3) ; R3 [48K,64K): V^T [128ch][64tok]
  __shared__ __align__(16) char sm[65536];

  const int tid = threadIdx.x;
  const int lane = tid & 63;
  const int wv_ = tid >> 6;       // wave id 0..7
  const int l15 = lane & 15;
  const int lg = lane >> 4;       // 0..3
  const int kgrp = lg * 8;        // k sub-offset inside a 32-wide k-step
  const int rsub = lg * 4;        // C/D row sub-base

  const int bid = blockIdx.x;
  const int b = bid >> 6;
  const int widx = bid & 63;
  const int wi = widx >> 3, wj = widx & 7;
  const long obase = (long)b * 56 * 56 * 128;

  // ---- X prefetch: each thread owns one row-chunk (row = tid>>3, 16 ch) ----
  const int xrow = tid >> 3;           // 0..63
  const int xk16 = (tid & 7) << 4;     // channel base 0..112
  long xoff = -1;
  if (xrow < 49) {
    int ty = div7(xrow), tx = xrow - ty * 7;
    int ih = wi * 7 + ty + 3; if (ih >= 56) ih -= 56;
    int iw = wj * 7 + tx + 3; if (iw >= 56) iw -= 56;
    xoff = obase + (long)((ih * 56 + iw) * 128 + xk16);
  }
  float xr[16];
#pragma unroll
  for (int i = 0; i < 16; ++i) xr[i] = 0.f;

  auto issue_x = [&](const float* src) {
    if (xoff >= 0) {
      const float* p = src + xoff;
#pragma unroll
      for (int q = 0; q < 4; ++q) {
        f32x4 v = *(const f32x4*)(p + q * 4);
        xr[q * 4 + 0] = v[0]; xr[q * 4 + 1] = v[1];
        xr[q * 4 + 2] = v[2]; xr[q * 4 + 3] = v[3];
      }
    }
  };
  auto write_x = [&]() {
    unsigned int w[8];
#pragma unroll
    for (int i = 0; i < 8; ++i)
      w[i] = (unsigned int)f2bf(xr[2 * i]) | ((unsigned int)f2bf(xr[2 * i + 1]) << 16);
    u32x4 a = {w[0], w[1], w[2], w[3]};
    u32x4 bb = {w[4], w[5], w[6], w[7]};
    *(u32x4*)(sm + swz256(xrow, xk16 * 2)) = a;
    *(u32x4*)(sm + swz256(xrow, xk16 * 2 + 16)) = bb;
  };

  // ---- linear: y = X @ W^T + bias ; wave w owns output cols [16w,16w+16) ----
  auto linear = [&](int woff, const float* bias, float scale, int mode, int dstbase) {
    const int n = wv_ * 16 + l15;
    s16x8 bfr[4];
#pragma unroll
    for (int kt = 0; kt < 4; ++kt)
      bfr[kt] = *(const s16x8*)(wsW + woff + n * 128 + kt * 32 + kgrp);
    float bval = bias[n] * scale;
#pragma unroll
    for (int mt = 0; mt < 4; ++mt) {
      f32x4 acc = {0.f, 0.f, 0.f, 0.f};
#pragma unroll
      for (int kt = 0; kt < 4; ++kt) {
        s16x8 afr = *(const s16x8*)(sm + swz256(mt * 16 + l15, (kt * 32 + kgrp) * 2));
        acc = MFMA16(afr, bfr[kt], acc);
      }
#pragma unroll
      for (int r = 0; r < 4; ++r) {
        float val = acc[r] * scale + bval;
        unsigned short h16 = f2bf(val);
        int row = mt * 16 + rsub + r;   // token index
        if (mode == 0)
          *(unsigned short*)(sm + dstbase + swz256(row, 2 * n)) = h16;
        else
          *(unsigned short*)(sm + 49152 + swz128(n, 2 * row)) = h16;
      }
    }
  };

  const float QSCALE = 0.17677669529663687f;  // 32^-0.5

  issue_x(xq);
  write_x(); __syncthreads();                       // B1: Xq visible
  issue_x(xk);                                      // Xk loads in flight under Q-GEMM
  linear(0, bq, QSCALE, 0, 16384); __syncthreads(); // B2: Q done, X(q) dead
  write_x(); __syncthreads();                       // B3: Xk visible
  issue_x(xv);
  linear(16384, bk, 1.f, 0, 32768); __syncthreads();// B4: K done, X(k) dead
  write_x(); __syncthreads();                       // B5: Xv visible
  linear(32768, bv, 1.f, 1, 0); __syncthreads();    // B6: V^T done, X dead

  // ---- attention: wave (h = wv&3, half = wv>>2) owns q-rows [32*half, 32*half+32) ----
  {
    const int h = wv_ & 3;
    const int half = wv_ >> 2;
    const int coff = h * 32;

    s16x8 kfr[4];
#pragma unroll
    for (int jt = 0; jt < 4; ++jt)
      kfr[jt] = *(const s16x8*)(sm + 32768 + swz256(jt * 16 + l15, (coff + kgrp) * 2));
    f32x4 S[2][4];
#pragma unroll
    for (int m2 = 0; m2 < 2; ++m2) {
      int mt = half * 2 + m2;
      s16x8 qfr = *(const s16x8*)(sm + 16384 + swz256(mt * 16 + l15, (coff + kgrp) * 2));
#pragma unroll
      for (int jt = 0; jt < 4; ++jt) {
        f32x4 z = {0.f, 0.f, 0.f, 0.f};
        S[m2][jt] = MFMA16(qfr, kfr[jt], z);
      }
    }

    // rpb + shift mask + pad-key masking
    const float* rpbh = rpbx + h * 2401;
    int jj[4], rgj[4]; bool jvld[4];
#pragma unroll
    for (int jt = 0; jt < 4; ++jt) {
      int j = jt * 16 + l15;
      jj[jt] = j; jvld[jt] = (j < 49);
      int jc = jvld[jt] ? j : 0;
      int yj = div7(jc), xj = jc - yj * 7;
      rgj[jt] = ((wi == 7) ? (yj < 4 ? 3 : 6) : 0) + ((wj == 7) ? (xj < 4 ? 1 : 2) : 0);
    }
#pragma unroll
    for (int m2 = 0; m2 < 2; ++m2) {
#pragma unroll
      for (int r = 0; r < 4; ++r) {
        int i = (half * 2 + m2) * 16 + rsub + r;
        if (i < 49) {
          int yi = div7(i), xi = i - yi * 7;
          int rgi = ((wi == 7) ? (yi < 4 ? 3 : 6) : 0) + ((wj == 7) ? (xi < 4 ? 1 : 2) : 0);
#pragma unroll
          for (int jt = 0; jt < 4; ++jt) {
            if (jvld[jt]) {
              float sv = S[m2][jt][r] + rpbh[i * 49 + jj[jt]];
              if (rgi != rgj[jt]) sv -= 100.f;
              S[m2][jt][r] = sv;
            } else {
              S[m2][jt][r] = -1e30f;
            }
          }
        } else {
#pragma unroll
          for (int jt = 0; jt < 4; ++jt)
            if (!jvld[jt]) S[m2][jt][r] = -1e30f;
        }
      }
    }

    // row softmax (rows live in 16-lane groups)
#pragma unroll
    for (int m2 = 0; m2 < 2; ++m2) {
#pragma unroll
      for (int r = 0; r < 4; ++r) {
        float m = fmaxf(fmaxf(S[m2][0][r], S[m2][1][r]), fmaxf(S[m2][2][r], S[m2][3][r]));
        for (int d = 1; d < 16; d <<= 1) m = fmaxf(m, __shfl_xor(m, d));
        float e0 = __expf(S[m2][0][r] - m);
        float e1 = __expf(S[m2][1][r] - m);
        float e2 = __expf(S[m2][2][r] - m);
        float e3 = __expf(S[m2][3][r] - m);
        float s = e0 + e1 + e2 + e3;
        for (int d = 1; d < 16; d <<= 1) s += __shfl_xor(s, d);
        float inv = 1.0f / s;
        S[m2][0][r] = e0 * inv; S[m2][1][r] = e1 * inv;
        S[m2][2][r] = e2 * inv; S[m2][3][r] = e3 * inv;
      }
    }
    __syncthreads();   // B7: all waves done reading Q/K before P overwrites them

    const int pbase = 16384 + h * 8192;  // P[64][64] bf16, swizzled, per head
#pragma unroll
    for (int m2 = 0; m2 < 2; ++m2)
#pragma unroll
      for (int r = 0; r < 4; ++r) {
        int i = (half * 2 + m2) * 16 + rsub + r;
#pragma unroll
        for (int jt = 0; jt < 4; ++jt)
          *(unsigned short*)(sm + pbase + swz128(i, 2 * (jt * 16 + l15))) = f2bf(S[m2][jt][r]);
      }
    __syncthreads();   // B8: P visible

    // PV : O = P @ V  (V^T in R3 so B-frags are contiguous)
    s16x8 vfr[2][2];
#pragma unroll
    for (int ks = 0; ks < 2; ++ks)
#pragma unroll
      for (int nt = 0; nt < 2; ++nt) {
        int c = coff + nt * 16 + l15;
        vfr[ks][nt] = *(const s16x8*)(sm + 49152 + swz128(c, (ks * 32 + kgrp) * 2));
      }
    f32x4 Oacc[2][2];
#pragma unroll
    for (int m2 = 0; m2 < 2; ++m2)
#pragma unroll
      for (int nt = 0; nt < 2; ++nt) Oacc[m2][nt] = (f32x4){0.f, 0.f, 0.f, 0.f};
#pragma unroll
    for (int m2 = 0; m2 < 2; ++m2) {
#pragma unroll
      for (int ks = 0; ks < 2; ++ks) {
        s16x8 pfr = *(const s16x8*)(sm + pbase + swz128((half * 2 + m2) * 16 + l15, (ks * 32 + kgrp) * 2));
        Oacc[m2][0] = MFMA16(pfr, vfr[ks][0], Oacc[m2][0]);
        Oacc[m2][1] = MFMA16(pfr, vfr[ks][1], Oacc[m2][1]);
      }
    }
    // O (bf16, row-major) into R0 (X buffer is dead)
#pragma unroll
    for (int m2 = 0; m2 < 2; ++m2)
#pragma unroll
      for (int nt = 0; nt < 2; ++nt)
#pragma unroll
        for (int r = 0; r < 4; ++r) {
          int row = (half * 2 + m2) * 16 + rsub + r;
          int c = coff + nt * 16 + l15;
          *(unsigned short*)(sm + swz256(row, 2 * c)) = f2bf(Oacc[m2][nt][r]);
        }
    __syncthreads();   // B9: O visible
  }

  // ---- proj + rolled scatter to global ----
  {
    const int woff = 49152;
    const int n = wv_ * 16 + l15;
    s16x8 bfr[4];
#pragma unroll
    for (int kt = 0; kt < 4; ++kt)
      bfr[kt] = *(const s16x8*)(wsW + woff + n * 128 + kt * 32 + kgrp);
    float bval = bp[n];
#pragma unroll
    for (int mt = 0; mt < 4; ++mt) {
      f32x4 acc = {0.f, 0.f, 0.f, 0.f};
#pragma unroll
      for (int kt = 0; kt < 4; ++kt) {
        s16x8 afr = *(const s16x8*)(sm + swz256(mt * 16 + l15, (kt * 32 + kgrp) * 2));
        acc = MFMA16(afr, bfr[kt], acc);
      }
#pragma unroll
      for (int r = 0; r < 4; ++r) {
        int tok = mt * 16 + rsub + r;
        if (tok < 49) {
          int ty = div7(tok), tx = tok - ty * 7;
          int oh = wi * 7 + ty + 3; if (oh >= 56) oh -= 56;
          int ow = wj * 7 + tx + 3; if (ow >= 56) ow -= 56;
          out[obase + (oh * 56 + ow) * 128 + n] = acc[r] + bval;
        }
      }
    }
  }
}

extern "C" void kernel_launch(void* const* d_in, const int* in_sizes, int n_in,
                              void* d_out, int out_size, void* d_ws, size_t ws_size,
                              hipStream_t stream) {
  const float* xq = (const float*)d_in[0];
  const float* xk = (const float*)d_in[1];
  const float* xv = (const float*)d_in[2];
  const float* wq = (const float*)d_in[3];
  const float* bq = (const float*)d_in[4];
  const float* wk = (const float*)d_in[5];
  const float* bk = (const float*)d_in[6];
  const float* wv = (const float*)d_in[7];
  const float* bv = (const float*)d_in[8];
  const float* wp = (const float*)d_in[9];
  const float* bp = (const float*)d_in[10];
  const float* rpb = (const float*)d_in[11];

  unsigned short* wsW = (unsigned short*)d_ws;                 // 4 x 16384 bf16 = 128 KB
  float* rpbx = (float*)((char*)d_ws + 131072);                // 4*49*49 fp32

  swin_prep<<<294, 256, 0, stream>>>(wq, wk, wv, wp, rpb, wsW, rpbx);

  float* out = (float*)d_out;
  swin_main<<<2048, 512, 0, stream>>>(xq, xk, xv, bq, bk, bv, bp, wsW, rpbx, out);
}

// Round 4
// 81.218 us; speedup vs baseline: 1.3601x; 1.1161x over previous
//
#include <hip/hip_runtime.h>
#include <hip/hip_bf16.h>

typedef __attribute__((ext_vector_type(8))) short s16x8;
typedef __attribute__((ext_vector_type(4))) float f32x4;
typedef __attribute__((ext_vector_type(2))) unsigned int u32x2;
typedef __attribute__((ext_vector_type(4))) unsigned int u32x4;

#define MFMA16(a, b, c) __builtin_amdgcn_mfma_f32_16x16x32_bf16((a), (b), (c), 0, 0, 0)
#define LOG2E 1.4426950408889634f

static __device__ __forceinline__ unsigned int pk2(float a, float b) {
  union { __hip_bfloat162 h2; unsigned int u; } cv;
  cv.h2 = __float22bfloat162_rn(make_float2(a, b));
  return cv.u;
}
static __device__ __forceinline__ int div7(int x) { return (x * 9363) >> 16; }  // exact 0..62
static __device__ __forceinline__ int swz256(int row, int byteoff) {
  return row * 256 + (byteoff ^ ((row & 7) << 4));
}
static __device__ __forceinline__ int swz128(int row, int byteoff) {
  return row * 128 + (byteoff ^ ((row & 7) << 4));
}

// ---------- prep: weights fp32->bf16 ; rpbm[case][head][64][64] = (rpb + mask)*log2e ----------
__global__ void swin_prep(const float* __restrict__ wq, const float* __restrict__ wk,
                          const float* __restrict__ wv, const float* __restrict__ wp,
                          const float* __restrict__ rpb_table,
                          unsigned short* __restrict__ wsW, float* __restrict__ rpbm) {
  int idx = blockIdx.x * 256 + threadIdx.x;
  if (idx < 65536) {
    int t = idx >> 14, loc = idx & 16383;
    const float* s = (t == 0) ? wq : (t == 1) ? wk : (t == 2) ? wv : wp;
    union { __hip_bfloat16 h; unsigned short u; } cv;
    cv.h = __float2bfloat16(s[loc]);
    wsW[idx] = cv.u;
  } else {
    int k = idx - 65536;               // [case(2b)][head(2b)][i(6b)][j(6b)]
    int c = k >> 14;
    int h = (k >> 12) & 3;
    int i = (k >> 6) & 63, j = k & 63;
    float val;
    if (j >= 49) val = -1e30f;
    else if (i >= 49) val = 0.f;
    else {
      int yi = div7(i), xi = i - yi * 7;
      int yj = div7(j), xj = j - yj * 7;
      int ridx = (yi - yj + 6) * 13 + (xi - xj + 6);
      val = rpb_table[ridx * 4 + h];
      int cwi = c >> 1, cwj = c & 1;
      int rgi = (cwi ? (yi < 4 ? 3 : 6) : 0) + (cwj ? (xi < 4 ? 1 : 2) : 0);
      int rgj = (cwi ? (yj < 4 ? 3 : 6) : 0) + (cwj ? (xj < 4 ? 1 : 2) : 0);
      if (rgi != rgj) val -= 100.f;
      val *= LOG2E;
    }
    rpbm[k] = val;
  }
}

// ---------- main: one 512-thread WG per (batch, window) ----------
__global__ __launch_bounds__(512, 4) void swin_main(
    const float* __restrict__ xq, const float* __restrict__ xk, const float* __restrict__ xv,
    const float* __restrict__ bq, const float* __restrict__ bk, const float* __restrict__ bv,
    const float* __restrict__ bp, const unsigned short* __restrict__ wsW,
    const float* __restrict__ rpbm, float* __restrict__ out) {
  // R0 [0,16K): X then O ; R1 [16K,32K): Q then P(h=0,1)
  // R2 [32K,48K): K then P(h=2,3) ; R3 [48K,64K): V^T [128ch][64tok]
  __shared__ __align__(16) char sm[65536];

  const int tid = threadIdx.x;
  const int lane = tid & 63;
  const int wv_ = tid >> 6;       // wave 0..7
  const int l15 = lane & 15;
  const int lg = lane >> 4;       // 0..3
  const int kgrp = lg * 8;
  const int rsub = lg * 4;

  const int bid = blockIdx.x;
  const int b = bid >> 6;
  const int widx = bid & 63;
  const int wi = widx >> 3, wj = widx & 7;
  const long obase = (long)b * 56 * 56 * 128;
  const int mcase = ((wi == 7) ? 2 : 0) + ((wj == 7) ? 1 : 0);

  // ---- X prefetch: thread owns (row = tid>>3, 16 ch) ----
  const int xrow = tid >> 3;
  const int xk16 = (tid & 7) << 4;
  long xoff = -1;
  if (xrow < 49) {
    int ty = div7(xrow), tx = xrow - ty * 7;
    int ih = wi * 7 + ty + 3; if (ih >= 56) ih -= 56;
    int iw = wj * 7 + tx + 3; if (iw >= 56) iw -= 56;
    xoff = obase + (long)((ih * 56 + iw) * 128 + xk16);
  }
  float xr[16];
#pragma unroll
  for (int i = 0; i < 16; ++i) xr[i] = 0.f;

  auto issue_x = [&](const float* src) {
    if (xoff >= 0) {
      const float* p = src + xoff;
#pragma unroll
      for (int q = 0; q < 4; ++q) {
        f32x4 v = *(const f32x4*)(p + q * 4);
        xr[q * 4 + 0] = v[0]; xr[q * 4 + 1] = v[1];
        xr[q * 4 + 2] = v[2]; xr[q * 4 + 3] = v[3];
      }
    }
  };
  auto write_x = [&]() {
    unsigned int w[8];
#pragma unroll
    for (int i = 0; i < 8; ++i) w[i] = pk2(xr[2 * i], xr[2 * i + 1]);
    u32x4 a = {w[0], w[1], w[2], w[3]};
    u32x4 bb = {w[4], w[5], w[6], w[7]};
    *(u32x4*)(sm + swz256(xrow, xk16 * 2)) = a;
    *(u32x4*)(sm + swz256(xrow, xk16 * 2 + 16)) = bb;
  };
  auto st2 = [&](int a0, int a1, float v0, float v1) {
    unsigned int u = pk2(v0, v1);
    *(unsigned short*)(sm + a0) = (unsigned short)u;
    *(unsigned short*)(sm + a1) = (unsigned short)(u >> 16);
  };

  // ---- linear: wave w owns output cols [16w, 16w+16) ----
  auto linear = [&](int woff, const float* bias, float scale, int mode, int dstbase) {
    const int n = wv_ * 16 + l15;
    s16x8 bfr[4];
#pragma unroll
    for (int kt = 0; kt < 4; ++kt)
      bfr[kt] = *(const s16x8*)(wsW + woff + n * 128 + kt * 32 + kgrp);
    float bval = bias[n] * scale;
#pragma unroll
    for (int mt = 0; mt < 4; ++mt) {
      f32x4 acc = {0.f, 0.f, 0.f, 0.f};
#pragma unroll
      for (int kt = 0; kt < 4; ++kt) {
        s16x8 afr = *(const s16x8*)(sm + swz256(mt * 16 + l15, (kt * 32 + kgrp) * 2));
        acc = MFMA16(afr, bfr[kt], acc);
      }
      float v0 = acc[0] * scale + bval, v1 = acc[1] * scale + bval;
      float v2 = acc[2] * scale + bval, v3 = acc[3] * scale + bval;
      int row0 = mt * 16 + rsub;
      if (mode == 0) {
        st2(dstbase + swz256(row0, 2 * n), dstbase + swz256(row0 + 1, 2 * n), v0, v1);
        st2(dstbase + swz256(row0 + 2, 2 * n), dstbase + swz256(row0 + 3, 2 * n), v2, v3);
      } else {
        // V^T: [ch n][tok row] -> rows row0..row0+3 are 8 contiguous bytes
        u32x2 pkw = {pk2(v0, v1), pk2(v2, v3)};
        *(u32x2*)(sm + 49152 + swz128(n, 2 * row0)) = pkw;
      }
    }
  };

  const float QSCALE = 0.17677669529663687f * LOG2E;  // 32^-0.5 * log2(e)

  issue_x(xq);
  write_x(); __syncthreads();                        // B1: Xq
  issue_x(xk);
  linear(0, bq, QSCALE, 0, 16384); __syncthreads();  // B2: Q done
  write_x(); __syncthreads();                        // B3: Xk
  issue_x(xv);
  linear(16384, bk, 1.f, 0, 32768); __syncthreads(); // B4: K done
  write_x(); __syncthreads();                        // B5: Xv

  // ---- fused phase: V-linear + QK^T + softmax (no barrier inside) ----
  const int h = wv_ & 3;
  const int half = wv_ >> 2;
  const int coff = h * 32;
  f32x4 S[2][4];
  {
    linear(32768, bv, 1.f, 1, 0);                    // V^T -> R3 (reads Xv in R0)

    // rpbm loads (L2-hot), issued before QK^T MFMAs
    const float* rpbm_h = rpbm + (((mcase << 2) + h) << 12);
    float rv[2][4][4];
#pragma unroll
    for (int m2 = 0; m2 < 2; ++m2)
#pragma unroll
      for (int r = 0; r < 4; ++r) {
        int i = (half * 2 + m2) * 16 + rsub + r;
        const float* rp = rpbm_h + i * 64 + l15;
#pragma unroll
        for (int jt = 0; jt < 4; ++jt) rv[m2][jt][r] = rp[jt * 16];
      }

    s16x8 kfr[4];
#pragma unroll
    for (int jt = 0; jt < 4; ++jt)
      kfr[jt] = *(const s16x8*)(sm + 32768 + swz256(jt * 16 + l15, (coff + kgrp) * 2));
#pragma unroll
    for (int m2 = 0; m2 < 2; ++m2) {
      int mt = half * 2 + m2;
      s16x8 qfr = *(const s16x8*)(sm + 16384 + swz256(mt * 16 + l15, (coff + kgrp) * 2));
#pragma unroll
      for (int jt = 0; jt < 4; ++jt) {
        f32x4 z = {0.f, 0.f, 0.f, 0.f};
        S[m2][jt] = MFMA16(qfr, kfr[jt], z);
      }
    }

    // S += rpbm (bias+mask+pad, pre-scaled by log2e)
#pragma unroll
    for (int m2 = 0; m2 < 2; ++m2)
#pragma unroll
      for (int jt = 0; jt < 4; ++jt)
#pragma unroll
        for (int r = 0; r < 4; ++r) S[m2][jt][r] += rv[m2][jt][r];

    // row softmax (base-2)
#pragma unroll
    for (int m2 = 0; m2 < 2; ++m2) {
#pragma unroll
      for (int r = 0; r < 4; ++r) {
        float m = fmaxf(fmaxf(S[m2][0][r], S[m2][1][r]), fmaxf(S[m2][2][r], S[m2][3][r]));
        for (int d = 1; d < 16; d <<= 1) m = fmaxf(m, __shfl_xor(m, d));
        float e0 = exp2f(S[m2][0][r] - m);
        float e1 = exp2f(S[m2][1][r] - m);
        float e2 = exp2f(S[m2][2][r] - m);
        float e3 = exp2f(S[m2][3][r] - m);
        float s = e0 + e1 + e2 + e3;
        for (int d = 1; d < 16; d <<= 1) s += __shfl_xor(s, d);
        float inv = 1.0f / s;
        S[m2][0][r] = e0 * inv; S[m2][1][r] = e1 * inv;
        S[m2][2][r] = e2 * inv; S[m2][3][r] = e3 * inv;
      }
    }
  }
  __syncthreads();   // B6: V^T complete; all Q/K + Xv reads done

  const int pbase = 16384 + h * 8192;  // P[64][64] bf16 per head
#pragma unroll
  for (int m2 = 0; m2 < 2; ++m2) {
    int i0 = (half * 2 + m2) * 16 + rsub;
#pragma unroll
    for (int jt = 0; jt < 4; ++jt) {
      int bo = 2 * (jt * 16 + l15);
      st2(pbase + swz128(i0, bo), pbase + swz128(i0 + 1, bo), S[m2][jt][0], S[m2][jt][1]);
      st2(pbase + swz128(i0 + 2, bo), pbase + swz128(i0 + 3, bo), S[m2][jt][2], S[m2][jt][3]);
    }
  }
  __syncthreads();   // B7: P visible

  {
    // PV : O = P @ V  (V^T so B-frags contiguous)
    s16x8 vfr[2][2];
#pragma unroll
    for (int ks = 0; ks < 2; ++ks)
#pragma unroll
      for (int nt = 0; nt < 2; ++nt) {
        int c = coff + nt * 16 + l15;
        vfr[ks][nt] = *(const s16x8*)(sm + 49152 + swz128(c, (ks * 32 + kgrp) * 2));
      }
    f32x4 Oacc[2][2];
#pragma unroll
    for (int m2 = 0; m2 < 2; ++m2)
#pragma unroll
      for (int nt = 0; nt < 2; ++nt) Oacc[m2][nt] = (f32x4){0.f, 0.f, 0.f, 0.f};
#pragma unroll
    for (int m2 = 0; m2 < 2; ++m2) {
#pragma unroll
      for (int ks = 0; ks < 2; ++ks) {
        s16x8 pfr = *(const s16x8*)(sm + pbase + swz128((half * 2 + m2) * 16 + l15, (ks * 32 + kgrp) * 2));
        Oacc[m2][0] = MFMA16(pfr, vfr[ks][0], Oacc[m2][0]);
        Oacc[m2][1] = MFMA16(pfr, vfr[ks][1], Oacc[m2][1]);
      }
    }
    // O (bf16 row-major) into R0
#pragma unroll
    for (int m2 = 0; m2 < 2; ++m2) {
      int row0 = (half * 2 + m2) * 16 + rsub;
#pragma unroll
      for (int nt = 0; nt < 2; ++nt) {
        int c2 = 2 * (coff + nt * 16 + l15);
        st2(swz256(row0, c2), swz256(row0 + 1, c2), Oacc[m2][nt][0], Oacc[m2][nt][1]);
        st2(swz256(row0 + 2, c2), swz256(row0 + 3, c2), Oacc[m2][nt][2], Oacc[m2][nt][3]);
      }
    }
  }
  __syncthreads();   // B8: O visible

  // ---- proj + rolled scatter ----
  {
    const int n = wv_ * 16 + l15;
    s16x8 bfr[4];
#pragma unroll
    for (int kt = 0; kt < 4; ++kt)
      bfr[kt] = *(const s16x8*)(wsW + 49152 + n * 128 + kt * 32 + kgrp);
    float bval = bp[n];
#pragma unroll
    for (int mt = 0; mt < 4; ++mt) {
      f32x4 acc = {0.f, 0.f, 0.f, 0.f};
#pragma unroll
      for (int kt = 0; kt < 4; ++kt) {
        s16x8 afr = *(const s16x8*)(sm + swz256(mt * 16 + l15, (kt * 32 + kgrp) * 2));
        acc = MFMA16(afr, bfr[kt], acc);
      }
#pragma unroll
      for (int r = 0; r < 4; ++r) {
        int tok = mt * 16 + rsub + r;
        if (tok < 49) {
          int ty = div7(tok), tx = tok - ty * 7;
          int oh = wi * 7 + ty + 3; if (oh >= 56) oh -= 56;
          int ow = wj * 7 + tx + 3; if (ow >= 56) ow -= 56;
          out[obase + (oh * 56 + ow) * 128 + n] = acc[r] + bval;
        }
      }
    }
  }
}

extern "C" void kernel_launch(void* const* d_in, const int* in_sizes, int n_in,
                              void* d_out, int out_size, void* d_ws, size_t ws_size,
                              hipStream_t stream) {
  const float* xq = (const float*)d_in[0];
  const float* xk = (const float*)d_in[1];
  const float* xv = (const float*)d_in[2];
  const float* wq = (const float*)d_in[3];
  const float* bq = (const float*)d_in[4];
  const float* wk = (const float*)d_in[5];
  const float* bk = (const float*)d_in[6];
  const float* wv = (const float*)d_in[7];
  const float* bv = (const float*)d_in[8];
  const float* wp = (const float*)d_in[9];
  const float* bp = (const float*)d_in[10];
  const float* rpb = (const float*)d_in[11];

  unsigned short* wsW = (unsigned short*)d_ws;          // 4 x 16384 bf16 = 128 KB
  float* rpbm = (float*)((char*)d_ws + 131072);         // 4*4*64*64 f32 = 256 KB

  swin_prep<<<512, 256, 0, stream>>>(wq, wk, wv, wp, rpb, wsW, rpbm);

  float* out = (float*)d_out;
  swin_main<<<2048, 512, 0, stream>>>(xq, xk, xv, bq, bk, bv, bp, wsW, rpbm, out);
}